// Round 3
// baseline (255.934 us; speedup 1.0000x reference)
//
#include <hip/hip_runtime.h>
#include <hip/hip_bf16.h>
#include <math.h>

#define EMBED 1024
#define HEADS 16
#define DH    64
#define BATCH 2
#define SEQ   2048

typedef __attribute__((ext_vector_type(8))) short bf16x8;
typedef __attribute__((ext_vector_type(4))) short bf16x4;
typedef __attribute__((ext_vector_type(4))) float f32x4;
typedef unsigned long long u64;

#define QSCALE 0.1803368801111244f   // 0.125 * log2(e): exp(s/8) == exp2(s*QSCALE)

static __device__ __forceinline__ unsigned short f2bf(float x) {
    unsigned u = __builtin_bit_cast(unsigned, x);
    return (unsigned short)((u + 0x7fffu + ((u >> 16) & 1u)) >> 16);
}
static __device__ __forceinline__ unsigned pk2bf(float a, float b) {
    union { __hip_bfloat162 h2; unsigned u; } c;
    c.h2 = __float22bfloat162_rn(make_float2(a, b));
    return c.u;
}
// async global->LDS DMA, 16 B per lane; LDS dest = wave-uniform base + lane*16
static __device__ __forceinline__ void gl_lds16(const void* g, void* l) {
    __builtin_amdgcn_global_load_lds(
        (const __attribute__((address_space(1))) void*)g,
        (__attribute__((address_space(3))) void*)l, 16, 0, 0);
}
// convert 16 consecutive fp32 (two float4 pairs) to one bf16x8 fragment
static __device__ __forceinline__ bf16x8 cvt8(const float* p) {
    float4 a = ((const float4*)p)[0];
    float4 b = ((const float4*)p)[1];
    union { unsigned u[4]; bf16x8 v; } c;
    c.u[0] = pk2bf(a.x, a.y); c.u[1] = pk2bf(a.z, a.w);
    c.u[2] = pk2bf(b.x, b.y); c.u[3] = pk2bf(b.z, b.w);
    return c.v;
}

// ---------------------------------------------------------------------------
// Kernel 1: QKV projection via MFMA — LDS-free version (R3).
// MFMA fragment layouts are loaded DIRECTLY from global fp32 and converted
// in-register: A row = lane&15 of the wave's (b,s), k = quad*8..; B n-col =
// lane&15 (W row), same k. No staging, no barrier. W (16 KB) is L1/L2-hot.
// grid = (1024, 3), block = 256.
// ---------------------------------------------------------------------------
__global__ __launch_bounds__(256) void proj_mfma(
    const float* __restrict__ q, const float* __restrict__ k, const float* __restrict__ v,
    const float* __restrict__ Wq, const float* __restrict__ bq,
    const float* __restrict__ Wk, const float* __restrict__ bk,
    const float* __restrict__ Wv, const float* __restrict__ bv,
    unsigned short* __restrict__ qh, unsigned short* __restrict__ kh,
    unsigned short* __restrict__ vh)
{
    const int blk = blockIdx.x;
    const int which = blockIdx.y;
    const float* x; const float* W; const float* bias; unsigned short* out;
    if (which == 0)      { x = q; W = Wq; bias = bq; out = qh; }
    else if (which == 1) { x = k; W = Wk; bias = bk; out = kh; }
    else                 { x = v; W = Wv; bias = bv; out = vh; }
    const float oscale = (which == 0) ? QSCALE : 1.0f;

    const int t    = threadIdx.x;
    const int w    = t >> 6;
    const int lane = t & 63;
    const int l15  = lane & 15;
    const int quad = lane >> 4;

    // A-fragments: X row = blk*64 + w*16 + l15 (one (b,s), 16 head-rows/wave)
    const float* xrow = x + ((size_t)blk * 64 + w * 16 + l15) * 64;
    const bf16x8 af0 = cvt8(xrow + quad * 8);
    const bf16x8 af1 = cvt8(xrow + 32 + quad * 8);

    f32x4 acc[4];
#pragma unroll
    for (int nt = 0; nt < 4; ++nt) {
        const float* wrow = W + (size_t)(nt * 16 + l15) * 64;
        bf16x8 bf0 = cvt8(wrow + quad * 8);
        bf16x8 bf1 = cvt8(wrow + 32 + quad * 8);
        f32x4 a = {0, 0, 0, 0};
        a = __builtin_amdgcn_mfma_f32_16x16x32_bf16(af0, bf0, a, 0, 0, 0);
        a = __builtin_amdgcn_mfma_f32_16x16x32_bf16(af1, bf1, a, 0, 0, 0);
        acc[nt] = a;
    }

    const int bsidx = blk * 4 + w;
    const int b = bsidx >> 11, s = bsidx & 2047;
#pragma unroll
    for (int nt = 0; nt < 4; ++nt) {
        const int d = nt * 16 + l15;
        const float bb = bias[d];
#pragma unroll
        for (int r = 0; r < 4; ++r) {
            const int h = quad * 4 + r;
            out[(((size_t)b * HEADS + h) * SEQ + s) * DH + d] =
                f2bf((acc[nt][r] + bb) * oscale);
        }
    }
}

// ---------------------------------------------------------------------------
// Kernel 2 (fused prep): vtrans (bid<1024) | maskpack-ballot (<1536) | wcvt
// maskpack rewritten (R3): lane l loads mask[word*64+l], __ballot(m!=0) IS
// the packed word — 1 load + 1 cmp per word vs 16 strided int4 + bit shuffle.
// ---------------------------------------------------------------------------
__global__ __launch_bounds__(256) void prep_kernel(
    const unsigned short* __restrict__ vh, unsigned short* __restrict__ vt,
    const int* __restrict__ mask, u64* __restrict__ bits,
    const float* __restrict__ Wo, unsigned short* __restrict__ Wob)
{
    __shared__ unsigned short Tt[64 * 72];
    const int bid = blockIdx.x;
    const int t   = threadIdx.x;

    if (bid < 1024) {                     // ---- V transpose ----
        const int st = bid & 31;
        const int bh = bid >> 5;
        const int r = t >> 2, p = t & 3;
        const unsigned short* src = vh + ((size_t)bh * SEQ + st * 64 + r) * DH + p * 16;
        *(uint4*)&Tt[r * 72 + p * 16]     = *(const uint4*)src;
        *(uint4*)&Tt[r * 72 + p * 16 + 8] = *(const uint4*)(src + 8);
        __syncthreads();
        union { unsigned short u[16]; uint4 v[2]; } o;
#pragma unroll
        for (int u = 0; u < 16; ++u) o.u[u] = Tt[(p * 16 + u) * 72 + r];
        unsigned short* dst = vt + ((size_t)bh * DH + r) * SEQ + st * 64 + p * 16;
        *(uint4*)dst       = o.v[0];
        *(uint4*)(dst + 8) = o.v[1];
    } else if (bid < 1536) {              // ---- mask -> bitmask via ballot ----
        const int wv   = (bid - 1024) * 4 + (t >> 6);   // wave 0..2047
        const int lane = t & 63;
        const size_t ebase = (size_t)wv * 64 * 64;      // 64 words x 64 elems
        u64 myw = 0;
#pragma unroll 8
        for (int i = 0; i < 64; ++i) {
            const int m = mask[ebase + (size_t)i * 64 + lane];
            const u64 bal = __ballot(m != 0);
            if (i == lane) myw = bal;
        }
        bits[(size_t)wv * 64 + lane] = myw;
    } else {                              // ---- Wo fp32 -> bf16 ----
        const int i = ((bid - 1536) * 256 + t) * 8;
        float4 a = ((const float4*)(Wo + i))[0];
        float4 b = ((const float4*)(Wo + i))[1];
        unsigned o32[4] = {pk2bf(a.x, a.y), pk2bf(a.z, a.w),
                           pk2bf(b.x, b.y), pk2bf(b.z, b.w)};
        *(uint4*)(Wob + i) = *(uint4*)o32;
    }
}

// ---------------------------------------------------------------------------
// Kernel 3: MFMA flash attention, double-buffered DMA K-loop, NO split-K.
// (unchanged from R2 — control for this round's aux-kernel changes)
// ---------------------------------------------------------------------------
__global__ __launch_bounds__(256, 4) void attn_kernel(
    const unsigned short* __restrict__ qh, const unsigned short* __restrict__ kh,
    const unsigned short* __restrict__ vt, const u64* __restrict__ mbits,
    unsigned short* __restrict__ ctx)
{
    const int bid = blockIdx.x;
    const int bh  = bid & 31;
    const int q0  = (bid >> 5) * 64;
    const int b   = bh >> 4;

    __shared__ unsigned char smem[32768];   // buf(16K) x2: [K 8K | V 8K]

    const int t    = threadIdx.x;
    const int w    = t >> 6;              // wave id: q-subtile (16 rows)
    const int lane = t & 63;
    const int l15  = lane & 15;
    const int quad = lane >> 4;

    const int srow   = lane >> 3;
    const int schunk = (lane & 7) ^ srow;

    const unsigned short* qb = qh + ((size_t)bh * SEQ + q0 + w * 16 + l15) * DH + quad * 8;
    const bf16x8 qf0 = *(const bf16x8*)qb;
    const bf16x8 qf1 = *(const bf16x8*)(qb + 32);

    f32x4 O[4];
#pragma unroll
    for (int dt = 0; dt < 4; ++dt) O[dt] = f32x4{0, 0, 0, 0};
    f32x4 Osum = {0, 0, 0, 0};
    const bf16x4 ones = {(short)0x3F80, (short)0x3F80, (short)0x3F80, (short)0x3F80};

    const unsigned short* kbase = kh + (size_t)bh * SEQ * DH
                                  + (size_t)srow * DH + schunk * 8;
    const unsigned short* vbase = vt + (size_t)bh * DH * SEQ
                                  + (size_t)srow * SEQ + schunk * 8;
    const u64* mrow = mbits + ((size_t)b * SEQ + q0 + w * 16 + l15) * (SEQ / 64);

    if (w < 2) {
        unsigned char* Kd = smem;
#pragma unroll
        for (int j = 0; j < 4; ++j) {
            const int i = w * 4 + j;
            gl_lds16(kbase + (size_t)i * 8 * DH, Kd + i * 1024);
        }
    } else {
        unsigned char* Vd = smem + 8192;
#pragma unroll
        for (int j = 0; j < 4; ++j) {
            const int i = (w - 2) * 4 + j;
            gl_lds16(vbase + (size_t)i * 8 * SEQ, Vd + i * 1024);
        }
    }
    u64 pm = mrow[0];
    __syncthreads();                      // drains DMA(0)

    for (int kt = 0; kt < 32; ++kt) {
        if (kt < 31) {
            const int bn = (kt + 1) & 1;
            if (w < 2) {
                unsigned char* Kd = smem + bn * 16384;
                const unsigned short* g0 = kbase + (size_t)(kt + 1) * 64 * DH;
#pragma unroll
                for (int j = 0; j < 4; ++j) {
                    const int i = w * 4 + j;
                    gl_lds16(g0 + (size_t)i * 8 * DH, Kd + i * 1024);
                }
            } else {
                unsigned char* Vd = smem + bn * 16384 + 8192;
                const unsigned short* g0 = vbase + (kt + 1) * 64;
#pragma unroll
                for (int j = 0; j < 4; ++j) {
                    const int i = (w - 2) * 4 + j;
                    gl_lds16(g0 + (size_t)i * 8 * SEQ, Vd + i * 1024);
                }
            }
        }
        const u64 mb = pm;
        if (kt < 31) pm = mrow[kt + 1];

        const unsigned short* KtH = (const unsigned short*)(smem + (kt & 1) * 16384);
        const unsigned short* VtH = KtH + 4096;

        const u64 mq = mb >> (quad * 4);
        bf16x4 p[4];
        const int rx = l15 & 7;
#pragma unroll
        for (int st = 0; st < 4; ++st) {
            const int r = st * 16 + l15;
            bf16x8 kf0 = *(const bf16x8*)&KtH[r * 64 + ((quad ^ rx)) * 8];
            bf16x8 kf1 = *(const bf16x8*)&KtH[r * 64 + ((quad ^ rx) ^ 4) * 8];
            f32x4 sa = {0, 0, 0, 0};
            sa = __builtin_amdgcn_mfma_f32_16x16x32_bf16(kf0, qf0, sa, 0, 0, 0);
            sa = __builtin_amdgcn_mfma_f32_16x16x32_bf16(kf1, qf1, sa, 0, 0, 0);
            const unsigned nib = (unsigned)(mq >> (st * 16)) & 0xFu;
            float p0 = (nib & 1u) ? exp2f(sa[0]) : 0.f;
            float p1 = (nib & 2u) ? exp2f(sa[1]) : 0.f;
            float p2 = (nib & 4u) ? exp2f(sa[2]) : 0.f;
            float p3 = (nib & 8u) ? exp2f(sa[3]) : 0.f;
            union { unsigned u2[2]; bf16x4 v; } pu;
            pu.u2[0] = pk2bf(p0, p1);
            pu.u2[1] = pk2bf(p2, p3);
            p[st] = pu.v;
            Osum = __builtin_amdgcn_mfma_f32_16x16x16bf16_1k(p[st], ones, Osum, 0, 0, 0);
        }

#pragma unroll
        for (int dt = 0; dt < 4; ++dt) {
            const int d = dt * 16 + l15;
            const int dx = l15 & 7;
#pragma unroll
            for (int st = 0; st < 4; ++st) {
                const int ch = (st * 2 + (quad >> 1)) ^ dx;
                bf16x4 vb = *(const bf16x4*)&VtH[d * 64 + ch * 8 + (quad & 1) * 4];
                O[dt] = __builtin_amdgcn_mfma_f32_16x16x16bf16_1k(p[st], vb, O[dt], 0, 0, 0);
            }
        }
        __syncthreads();
    }

    float inv[4];
#pragma unroll
    for (int r = 0; r < 4; ++r) inv[r] = 1.0f / Osum[r];
#pragma unroll
    for (int r = 0; r < 4; ++r) {
        const int row = q0 + w * 16 + quad * 4 + r;
        unsigned short* dst = ctx + ((size_t)bh * SEQ + row) * DH + l15;
#pragma unroll
        for (int dt = 0; dt < 4; ++dt)
            dst[dt * 16] = f2bf(O[dt][r] * inv[r]);
    }
}

// ---------------------------------------------------------------------------
// Kernel 4: output projection via MFMA, DMA-staged + double-buffered.
// (unchanged)
// ---------------------------------------------------------------------------
__global__ __launch_bounds__(256, 4) void outproj_mfma(
    const unsigned short* __restrict__ ctx, const unsigned short* __restrict__ Wob,
    const float* __restrict__ bo, float* __restrict__ out)
{
    const int n0 = blockIdx.x * 64;
    const int m0 = blockIdx.y * 64;
    const int b  = m0 / SEQ;
    const int s0 = m0 % SEQ;

    __shared__ unsigned char smem[32768];   // buf(16K) x2: [A 8K | W 8K]

    const int t    = threadIdx.x;
    const int w    = t >> 6;
    const int lane = t & 63;
    const int l15  = lane & 15;
    const int quad = lane >> 4;
    const int srow   = lane >> 3;
    const int schunk = (lane & 7) ^ srow;

    const unsigned short* abase = ctx + ((size_t)b * HEADS * SEQ + s0 + srow) * DH + schunk * 8;
    const unsigned short* wbase = Wob + (size_t)(n0 + srow) * EMBED + schunk * 8;

    f32x4 acc[4] = {f32x4{0,0,0,0}, f32x4{0,0,0,0}, f32x4{0,0,0,0}, f32x4{0,0,0,0}};

    {
        unsigned char* Ab = smem;
        unsigned char* Wb = smem + 8192;
#pragma unroll
        for (int j = 0; j < 4; ++j) {
            const int idx = w * 4 + j;
            if (idx < 8)
                gl_lds16(abase + (size_t)idx * 8 * DH, Ab + idx * 1024);
            else
                gl_lds16(wbase + (size_t)(idx - 8) * 8 * EMBED, Wb + (idx - 8) * 1024);
        }
    }
    __syncthreads();

    for (int kt = 0; kt < 16; ++kt) {
        if (kt < 15) {
            const int ktn = kt + 1;
            unsigned char* Ab = smem + (ktn & 1) * 16384;
            unsigned char* Wb = Ab + 8192;
#pragma unroll
            for (int j = 0; j < 4; ++j) {
                const int idx = w * 4 + j;
                if (idx < 8)
                    gl_lds16(abase + (size_t)ktn * SEQ * DH + (size_t)idx * 8 * DH,
                             Ab + idx * 1024);
                else
                    gl_lds16(wbase + (size_t)(idx - 8) * 8 * EMBED + ktn * 64,
                             Wb + (idx - 8) * 1024);
            }
        }

        const unsigned short* At = (const unsigned short*)(smem + (kt & 1) * 16384);
        const unsigned short* Wt = At + 4096;
        const int rx = l15 & 7;
        const int c0 = ((quad ^ rx)) * 8;

        bf16x8 bf0 = *(const bf16x8*)&Wt[(w * 16 + l15) * 64 + c0];
        bf16x8 bf1 = *(const bf16x8*)&Wt[(w * 16 + l15) * 64 + (c0 ^ 32)];
#pragma unroll
        for (int mt = 0; mt < 4; ++mt) {
            bf16x8 af0 = *(const bf16x8*)&At[(mt * 16 + l15) * 64 + c0];
            bf16x8 af1 = *(const bf16x8*)&At[(mt * 16 + l15) * 64 + (c0 ^ 32)];
            acc[mt] = __builtin_amdgcn_mfma_f32_16x16x32_bf16(af0, bf0, acc[mt], 0, 0, 0);
            acc[mt] = __builtin_amdgcn_mfma_f32_16x16x32_bf16(af1, bf1, acc[mt], 0, 0, 0);
        }
        __syncthreads();
    }

    const float bv = bo[n0 + w * 16 + l15];
#pragma unroll
    for (int mt = 0; mt < 4; ++mt) {
#pragma unroll
        for (int r = 0; r < 4; ++r) {
            out[(size_t)(m0 + mt * 16 + quad * 4 + r) * EMBED + n0 + w * 16 + l15] =
                acc[mt][r] + bv;
        }
    }
}

// ---------------------------------------------------------------------------
extern "C" void kernel_launch(void* const* d_in, const int* in_sizes, int n_in,
                              void* d_out, int out_size, void* d_ws, size_t ws_size,
                              hipStream_t stream) {
    const float* k    = (const float*)d_in[0];
    const float* q    = (const float*)d_in[1];
    const float* v    = (const float*)d_in[2];
    const int*   mask = (const int*)  d_in[3];
    const float* Wk   = (const float*)d_in[4];
    const float* bk   = (const float*)d_in[5];
    const float* Wq   = (const float*)d_in[6];
    const float* bq   = (const float*)d_in[7];
    const float* Wv   = (const float*)d_in[8];
    const float* bv   = (const float*)d_in[9];
    const float* Wo   = (const float*)d_in[10];
    const float* bo   = (const float*)d_in[11];
    float* out = (float*)d_out;

    const size_t TEN = (size_t)BATCH * HEADS * SEQ * DH;   // 4,194,304 elems
    unsigned short* qh_bf = (unsigned short*)d_ws;         // 8 MB
    unsigned short* kh_bf = qh_bf + TEN;                   // 8 MB
    unsigned short* vh_bf = kh_bf + TEN;                   // 8 MB
    unsigned short* vt_bf = vh_bf + TEN;                   // 8 MB
    unsigned short* ctxb  = vt_bf + TEN;                   // 8 MB
    unsigned short* Wob   = ctxb + TEN;                    // 2 MB
    u64*            mbits = (u64*)(Wob + EMBED * EMBED);   // 1 MB  (43 MB total)

    proj_mfma<<<dim3(BATCH * SEQ * HEADS / 64, 3), 256, 0, stream>>>(
        q, k, v, Wq, bq, Wk, bk, Wv, bv, qh_bf, kh_bf, vh_bf);
    prep_kernel<<<dim3(2048), 256, 0, stream>>>(
        vh_bf, vt_bf, mask, mbits, Wo, Wob);
    attn_kernel<<<dim3((SEQ / 64) * BATCH * HEADS), 256, 0, stream>>>(
        qh_bf, kh_bf, vt_bf, mbits, ctxb);
    outproj_mfma<<<dim3(EMBED / 64, BATCH * SEQ / 64), 256, 0, stream>>>(
        ctxb, Wob, bo, out);
}

// Round 4
// 239.970 us; speedup vs baseline: 1.0665x; 1.0665x over previous
//
#include <hip/hip_runtime.h>
#include <hip/hip_bf16.h>
#include <math.h>

#define EMBED 1024
#define HEADS 16
#define DH    64
#define BATCH 2
#define SEQ   2048

typedef __attribute__((ext_vector_type(8))) short bf16x8;
typedef __attribute__((ext_vector_type(4))) short bf16x4;
typedef __attribute__((ext_vector_type(4))) float f32x4;
typedef unsigned long long u64;

#define QSCALE 0.1803368801111244f   // 0.125 * log2(e): exp(s/8) == exp2(s*QSCALE)

static __device__ __forceinline__ unsigned short f2bf(float x) {
    unsigned u = __builtin_bit_cast(unsigned, x);
    return (unsigned short)((u + 0x7fffu + ((u >> 16) & 1u)) >> 16);
}
static __device__ __forceinline__ unsigned pk2bf(float a, float b) {
    union { __hip_bfloat162 h2; unsigned u; } c;
    c.h2 = __float22bfloat162_rn(make_float2(a, b));
    return c.u;
}
// async global->LDS DMA, 16 B per lane; LDS dest = wave-uniform base + lane*16
static __device__ __forceinline__ void gl_lds16(const void* g, void* l) {
    __builtin_amdgcn_global_load_lds(
        (const __attribute__((address_space(1))) void*)g,
        (__attribute__((address_space(3))) void*)l, 16, 0, 0);
}
// convert 16 consecutive fp32 (two float4 pairs) to one bf16x8 fragment
static __device__ __forceinline__ bf16x8 cvt8(const float* p) {
    float4 a = ((const float4*)p)[0];
    float4 b = ((const float4*)p)[1];
    union { unsigned u[4]; bf16x8 v; } c;
    c.u[0] = pk2bf(a.x, a.y); c.u[1] = pk2bf(a.z, a.w);
    c.u[2] = pk2bf(b.x, b.y); c.u[3] = pk2bf(b.z, b.w);
    return c.v;
}

// ---------------------------------------------------------------------------
// Kernel 1: QKV projection via MFMA (R4 hybrid).
// X A-frags load DIRECTLY from global fp32 (verified in R3: lane's fragment is
// 2x32B contiguous) and are issued BEFORE the barrier to overlap W staging.
// W is cooperatively staged/converted in LDS once per block (verified R2
// layout, 72-ushort stride). One barrier, half of R2's staging traffic.
// grid = (1024, 3), block = 256.
// ---------------------------------------------------------------------------
__global__ __launch_bounds__(256) void proj_mfma(
    const float* __restrict__ q, const float* __restrict__ k, const float* __restrict__ v,
    const float* __restrict__ Wq, const float* __restrict__ bq,
    const float* __restrict__ Wk, const float* __restrict__ bk,
    const float* __restrict__ Wv, const float* __restrict__ bv,
    unsigned short* __restrict__ qh, unsigned short* __restrict__ kh,
    unsigned short* __restrict__ vh)
{
    const int blk = blockIdx.x;
    const int which = blockIdx.y;
    const float* x; const float* W; const float* bias; unsigned short* out;
    if (which == 0)      { x = q; W = Wq; bias = bq; out = qh; }
    else if (which == 1) { x = k; W = Wk; bias = bk; out = kh; }
    else                 { x = v; W = Wv; bias = bv; out = vh; }
    const float oscale = (which == 0) ? QSCALE : 1.0f;

    __shared__ unsigned short Ws[64 * 72];

    const int t    = threadIdx.x;
    const int w    = t >> 6;
    const int lane = t & 63;
    const int l15  = lane & 15;
    const int quad = lane >> 4;

    // ---- stage W into LDS (cooperative, one pass) ----
    const int sr = t >> 2, sp = t & 3;
    {
        const float* wsrc = W + (size_t)sr * 64 + sp * 16;
        unsigned o32[8];
#pragma unroll
        for (int u4 = 0; u4 < 4; ++u4) {
            float4 a = ((const float4*)wsrc)[u4];
            o32[u4 * 2 + 0] = pk2bf(a.x, a.y);
            o32[u4 * 2 + 1] = pk2bf(a.z, a.w);
        }
        *(uint4*)&Ws[sr * 72 + sp * 16]     = *(uint4*)&o32[0];
        *(uint4*)&Ws[sr * 72 + sp * 16 + 8] = *(uint4*)&o32[4];
    }

    // ---- X A-frags direct from global (overlaps W staging; barrier below) ----
    const float* xrow = x + ((size_t)blk * 64 + w * 16 + l15) * 64;
    const bf16x8 af0 = cvt8(xrow + quad * 8);
    const bf16x8 af1 = cvt8(xrow + 32 + quad * 8);

    __syncthreads();

    f32x4 acc[4];
#pragma unroll
    for (int nt = 0; nt < 4; ++nt) {
        bf16x8 bf0 = *(const bf16x8*)&Ws[(nt * 16 + l15) * 72 + quad * 8];
        bf16x8 bf1 = *(const bf16x8*)&Ws[(nt * 16 + l15) * 72 + 32 + quad * 8];
        f32x4 a = {0, 0, 0, 0};
        a = __builtin_amdgcn_mfma_f32_16x16x32_bf16(af0, bf0, a, 0, 0, 0);
        a = __builtin_amdgcn_mfma_f32_16x16x32_bf16(af1, bf1, a, 0, 0, 0);
        acc[nt] = a;
    }

    const int bsidx = blk * 4 + w;
    const int b = bsidx >> 11, s = bsidx & 2047;
#pragma unroll
    for (int nt = 0; nt < 4; ++nt) {
        const int d = nt * 16 + l15;
        const float bb = bias[d];
#pragma unroll
        for (int r = 0; r < 4; ++r) {
            const int h = quad * 4 + r;
            out[(((size_t)b * HEADS + h) * SEQ + s) * DH + d] =
                f2bf((acc[nt][r] + bb) * oscale);
        }
    }
}

// ---------------------------------------------------------------------------
// Kernel 2 (fused prep): vtrans (bid<1024) | maskpack (<1536) | wcvt (rest)
// maskpack reverted to the R2 int4 form: 16 independent vector loads +
// parallel bit-assembly (the R3 ballot version serialized 64 vcc-dependent
// iterations per wave and regressed).
// ---------------------------------------------------------------------------
__global__ __launch_bounds__(256) void prep_kernel(
    const unsigned short* __restrict__ vh, unsigned short* __restrict__ vt,
    const int* __restrict__ mask, u64* __restrict__ bits,
    const float* __restrict__ Wo, unsigned short* __restrict__ Wob)
{
    __shared__ unsigned short Tt[64 * 72];
    const int bid = blockIdx.x;
    const int t   = threadIdx.x;

    if (bid < 1024) {                     // ---- V transpose ----
        const int st = bid & 31;
        const int bh = bid >> 5;
        const int r = t >> 2, p = t & 3;
        const unsigned short* src = vh + ((size_t)bh * SEQ + st * 64 + r) * DH + p * 16;
        *(uint4*)&Tt[r * 72 + p * 16]     = *(const uint4*)src;
        *(uint4*)&Tt[r * 72 + p * 16 + 8] = *(const uint4*)(src + 8);
        __syncthreads();
        union { unsigned short u[16]; uint4 v[2]; } o;
#pragma unroll
        for (int u = 0; u < 16; ++u) o.u[u] = Tt[(p * 16 + u) * 72 + r];
        unsigned short* dst = vt + ((size_t)bh * DH + r) * SEQ + st * 64 + p * 16;
        *(uint4*)dst       = o.v[0];
        *(uint4*)(dst + 8) = o.v[1];
    } else if (bid < 1536) {              // ---- mask -> bitmask ----
        const int idx = (bid - 1024) * 256 + t;
        const int4* src = (const int4*)(mask + (size_t)idx * 64);
        u64 w = 0;
#pragma unroll
        for (int u = 0; u < 16; ++u) {
            int4 m = src[u];
            u64 nib = (m.x != 0 ? 1ull : 0) | (m.y != 0 ? 2ull : 0) |
                      (m.z != 0 ? 4ull : 0) | (m.w != 0 ? 8ull : 0);
            w |= nib << (u * 4);
        }
        bits[idx] = w;
    } else {                              // ---- Wo fp32 -> bf16 ----
        const int i = ((bid - 1536) * 256 + t) * 8;
        float4 a = ((const float4*)(Wo + i))[0];
        float4 b = ((const float4*)(Wo + i))[1];
        unsigned o32[4] = {pk2bf(a.x, a.y), pk2bf(a.z, a.w),
                           pk2bf(b.x, b.y), pk2bf(b.z, b.w)};
        *(uint4*)(Wob + i) = *(uint4*)o32;
    }
}

// ---------------------------------------------------------------------------
// Kernel 3: MFMA flash attention, double-buffered DMA K-loop, NO split-K.
// (frozen since R2 — control; 84.9 us, MfmaUtil 30, conflicts 8.39M)
// ---------------------------------------------------------------------------
__global__ __launch_bounds__(256, 4) void attn_kernel(
    const unsigned short* __restrict__ qh, const unsigned short* __restrict__ kh,
    const unsigned short* __restrict__ vt, const u64* __restrict__ mbits,
    unsigned short* __restrict__ ctx)
{
    const int bid = blockIdx.x;
    const int bh  = bid & 31;
    const int q0  = (bid >> 5) * 64;
    const int b   = bh >> 4;

    __shared__ unsigned char smem[32768];   // buf(16K) x2: [K 8K | V 8K]

    const int t    = threadIdx.x;
    const int w    = t >> 6;              // wave id: q-subtile (16 rows)
    const int lane = t & 63;
    const int l15  = lane & 15;
    const int quad = lane >> 4;

    const int srow   = lane >> 3;
    const int schunk = (lane & 7) ^ srow;

    const unsigned short* qb = qh + ((size_t)bh * SEQ + q0 + w * 16 + l15) * DH + quad * 8;
    const bf16x8 qf0 = *(const bf16x8*)qb;
    const bf16x8 qf1 = *(const bf16x8*)(qb + 32);

    f32x4 O[4];
#pragma unroll
    for (int dt = 0; dt < 4; ++dt) O[dt] = f32x4{0, 0, 0, 0};
    f32x4 Osum = {0, 0, 0, 0};
    const bf16x4 ones = {(short)0x3F80, (short)0x3F80, (short)0x3F80, (short)0x3F80};

    const unsigned short* kbase = kh + (size_t)bh * SEQ * DH
                                  + (size_t)srow * DH + schunk * 8;
    const unsigned short* vbase = vt + (size_t)bh * DH * SEQ
                                  + (size_t)srow * SEQ + schunk * 8;
    const u64* mrow = mbits + ((size_t)b * SEQ + q0 + w * 16 + l15) * (SEQ / 64);

    if (w < 2) {
        unsigned char* Kd = smem;
#pragma unroll
        for (int j = 0; j < 4; ++j) {
            const int i = w * 4 + j;
            gl_lds16(kbase + (size_t)i * 8 * DH, Kd + i * 1024);
        }
    } else {
        unsigned char* Vd = smem + 8192;
#pragma unroll
        for (int j = 0; j < 4; ++j) {
            const int i = (w - 2) * 4 + j;
            gl_lds16(vbase + (size_t)i * 8 * SEQ, Vd + i * 1024);
        }
    }
    u64 pm = mrow[0];
    __syncthreads();                      // drains DMA(0)

    for (int kt = 0; kt < 32; ++kt) {
        if (kt < 31) {
            const int bn = (kt + 1) & 1;
            if (w < 2) {
                unsigned char* Kd = smem + bn * 16384;
                const unsigned short* g0 = kbase + (size_t)(kt + 1) * 64 * DH;
#pragma unroll
                for (int j = 0; j < 4; ++j) {
                    const int i = w * 4 + j;
                    gl_lds16(g0 + (size_t)i * 8 * DH, Kd + i * 1024);
                }
            } else {
                unsigned char* Vd = smem + bn * 16384 + 8192;
                const unsigned short* g0 = vbase + (kt + 1) * 64;
#pragma unroll
                for (int j = 0; j < 4; ++j) {
                    const int i = (w - 2) * 4 + j;
                    gl_lds16(g0 + (size_t)i * 8 * SEQ, Vd + i * 1024);
                }
            }
        }
        const u64 mb = pm;
        if (kt < 31) pm = mrow[kt + 1];

        const unsigned short* KtH = (const unsigned short*)(smem + (kt & 1) * 16384);
        const unsigned short* VtH = KtH + 4096;

        const u64 mq = mb >> (quad * 4);
        bf16x4 p[4];
        const int rx = l15 & 7;
#pragma unroll
        for (int st = 0; st < 4; ++st) {
            const int r = st * 16 + l15;
            bf16x8 kf0 = *(const bf16x8*)&KtH[r * 64 + ((quad ^ rx)) * 8];
            bf16x8 kf1 = *(const bf16x8*)&KtH[r * 64 + ((quad ^ rx) ^ 4) * 8];
            f32x4 sa = {0, 0, 0, 0};
            sa = __builtin_amdgcn_mfma_f32_16x16x32_bf16(kf0, qf0, sa, 0, 0, 0);
            sa = __builtin_amdgcn_mfma_f32_16x16x32_bf16(kf1, qf1, sa, 0, 0, 0);
            const unsigned nib = (unsigned)(mq >> (st * 16)) & 0xFu;
            float p0 = (nib & 1u) ? exp2f(sa[0]) : 0.f;
            float p1 = (nib & 2u) ? exp2f(sa[1]) : 0.f;
            float p2 = (nib & 4u) ? exp2f(sa[2]) : 0.f;
            float p3 = (nib & 8u) ? exp2f(sa[3]) : 0.f;
            union { unsigned u2[2]; bf16x4 v; } pu;
            pu.u2[0] = pk2bf(p0, p1);
            pu.u2[1] = pk2bf(p2, p3);
            p[st] = pu.v;
            Osum = __builtin_amdgcn_mfma_f32_16x16x16bf16_1k(p[st], ones, Osum, 0, 0, 0);
        }

#pragma unroll
        for (int dt = 0; dt < 4; ++dt) {
            const int d = dt * 16 + l15;
            const int dx = l15 & 7;
#pragma unroll
            for (int st = 0; st < 4; ++st) {
                const int ch = (st * 2 + (quad >> 1)) ^ dx;
                bf16x4 vb = *(const bf16x4*)&VtH[d * 64 + ch * 8 + (quad & 1) * 4];
                O[dt] = __builtin_amdgcn_mfma_f32_16x16x16bf16_1k(p[st], vb, O[dt], 0, 0, 0);
            }
        }
        __syncthreads();
    }

    float inv[4];
#pragma unroll
    for (int r = 0; r < 4; ++r) inv[r] = 1.0f / Osum[r];
#pragma unroll
    for (int r = 0; r < 4; ++r) {
        const int row = q0 + w * 16 + quad * 4 + r;
        unsigned short* dst = ctx + ((size_t)bh * SEQ + row) * DH + l15;
#pragma unroll
        for (int dt = 0; dt < 4; ++dt)
            dst[dt * 16] = f2bf(O[dt][r] * inv[r]);
    }
}

// ---------------------------------------------------------------------------
// Kernel 4: output projection via MFMA, DMA-staged + double-buffered.
// (frozen)
// ---------------------------------------------------------------------------
__global__ __launch_bounds__(256, 4) void outproj_mfma(
    const unsigned short* __restrict__ ctx, const unsigned short* __restrict__ Wob,
    const float* __restrict__ bo, float* __restrict__ out)
{
    const int n0 = blockIdx.x * 64;
    const int m0 = blockIdx.y * 64;
    const int b  = m0 / SEQ;
    const int s0 = m0 % SEQ;

    __shared__ unsigned char smem[32768];   // buf(16K) x2: [A 8K | W 8K]

    const int t    = threadIdx.x;
    const int w    = t >> 6;
    const int lane = t & 63;
    const int l15  = lane & 15;
    const int quad = lane >> 4;
    const int srow   = lane >> 3;
    const int schunk = (lane & 7) ^ srow;

    const unsigned short* abase = ctx + ((size_t)b * HEADS * SEQ + s0 + srow) * DH + schunk * 8;
    const unsigned short* wbase = Wob + (size_t)(n0 + srow) * EMBED + schunk * 8;

    f32x4 acc[4] = {f32x4{0,0,0,0}, f32x4{0,0,0,0}, f32x4{0,0,0,0}, f32x4{0,0,0,0}};

    {
        unsigned char* Ab = smem;
        unsigned char* Wb = smem + 8192;
#pragma unroll
        for (int j = 0; j < 4; ++j) {
            const int idx = w * 4 + j;
            if (idx < 8)
                gl_lds16(abase + (size_t)idx * 8 * DH, Ab + idx * 1024);
            else
                gl_lds16(wbase + (size_t)(idx - 8) * 8 * EMBED, Wb + (idx - 8) * 1024);
        }
    }
    __syncthreads();

    for (int kt = 0; kt < 16; ++kt) {
        if (kt < 15) {
            const int ktn = kt + 1;
            unsigned char* Ab = smem + (ktn & 1) * 16384;
            unsigned char* Wb = Ab + 8192;
#pragma unroll
            for (int j = 0; j < 4; ++j) {
                const int idx = w * 4 + j;
                if (idx < 8)
                    gl_lds16(abase + (size_t)ktn * SEQ * DH + (size_t)idx * 8 * DH,
                             Ab + idx * 1024);
                else
                    gl_lds16(wbase + (size_t)(idx - 8) * 8 * EMBED + ktn * 64,
                             Wb + (idx - 8) * 1024);
            }
        }

        const unsigned short* At = (const unsigned short*)(smem + (kt & 1) * 16384);
        const unsigned short* Wt = At + 4096;
        const int rx = l15 & 7;
        const int c0 = ((quad ^ rx)) * 8;

        bf16x8 bf0 = *(const bf16x8*)&Wt[(w * 16 + l15) * 64 + c0];
        bf16x8 bf1 = *(const bf16x8*)&Wt[(w * 16 + l15) * 64 + (c0 ^ 32)];
#pragma unroll
        for (int mt = 0; mt < 4; ++mt) {
            bf16x8 af0 = *(const bf16x8*)&At[(mt * 16 + l15) * 64 + c0];
            bf16x8 af1 = *(const bf16x8*)&At[(mt * 16 + l15) * 64 + (c0 ^ 32)];
            acc[mt] = __builtin_amdgcn_mfma_f32_16x16x32_bf16(af0, bf0, acc[mt], 0, 0, 0);
            acc[mt] = __builtin_amdgcn_mfma_f32_16x16x32_bf16(af1, bf1, acc[mt], 0, 0, 0);
        }
        __syncthreads();
    }

    const float bv = bo[n0 + w * 16 + l15];
#pragma unroll
    for (int mt = 0; mt < 4; ++mt) {
#pragma unroll
        for (int r = 0; r < 4; ++r) {
            out[(size_t)(m0 + mt * 16 + quad * 4 + r) * EMBED + n0 + w * 16 + l15] =
                acc[mt][r] + bv;
        }
    }
}

// ---------------------------------------------------------------------------
extern "C" void kernel_launch(void* const* d_in, const int* in_sizes, int n_in,
                              void* d_out, int out_size, void* d_ws, size_t ws_size,
                              hipStream_t stream) {
    const float* k    = (const float*)d_in[0];
    const float* q    = (const float*)d_in[1];
    const float* v    = (const float*)d_in[2];
    const int*   mask = (const int*)  d_in[3];
    const float* Wk   = (const float*)d_in[4];
    const float* bk   = (const float*)d_in[5];
    const float* Wq   = (const float*)d_in[6];
    const float* bq   = (const float*)d_in[7];
    const float* Wv   = (const float*)d_in[8];
    const float* bv   = (const float*)d_in[9];
    const float* Wo   = (const float*)d_in[10];
    const float* bo   = (const float*)d_in[11];
    float* out = (float*)d_out;

    const size_t TEN = (size_t)BATCH * HEADS * SEQ * DH;   // 4,194,304 elems
    unsigned short* qh_bf = (unsigned short*)d_ws;         // 8 MB
    unsigned short* kh_bf = qh_bf + TEN;                   // 8 MB
    unsigned short* vh_bf = kh_bf + TEN;                   // 8 MB
    unsigned short* vt_bf = vh_bf + TEN;                   // 8 MB
    unsigned short* ctxb  = vt_bf + TEN;                   // 8 MB
    unsigned short* Wob   = ctxb + TEN;                    // 2 MB
    u64*            mbits = (u64*)(Wob + EMBED * EMBED);   // 1 MB  (43 MB total)

    proj_mfma<<<dim3(BATCH * SEQ * HEADS / 64, 3), 256, 0, stream>>>(
        q, k, v, Wq, bq, Wk, bk, Wv, bv, qh_bf, kh_bf, vh_bf);
    prep_kernel<<<dim3(2048), 256, 0, stream>>>(
        vh_bf, vt_bf, mask, mbits, Wo, Wob);
    attn_kernel<<<dim3((SEQ / 64) * BATCH * HEADS), 256, 0, stream>>>(
        qh_bf, kh_bf, vt_bf, mbits, ctxb);
    outproj_mfma<<<dim3(EMBED / 64, BATCH * SEQ / 64), 256, 0, stream>>>(
        ctxb, Wob, bo, out);
}

// Round 5
// 239.966 us; speedup vs baseline: 1.0665x; 1.0000x over previous
//
#include <hip/hip_runtime.h>
#include <hip/hip_bf16.h>
#include <math.h>

#define EMBED 1024
#define HEADS 16
#define DH    64
#define BATCH 2
#define SEQ   2048

typedef __attribute__((ext_vector_type(8))) short bf16x8;
typedef __attribute__((ext_vector_type(4))) short bf16x4;
typedef __attribute__((ext_vector_type(4))) float f32x4;
typedef unsigned long long u64;

#define QSCALE 0.1803368801111244f   // 0.125 * log2(e): exp(s/8) == exp2(s*QSCALE)

static __device__ __forceinline__ unsigned short f2bf(float x) {
    unsigned u = __builtin_bit_cast(unsigned, x);
    return (unsigned short)((u + 0x7fffu + ((u >> 16) & 1u)) >> 16);
}
static __device__ __forceinline__ unsigned pk2bf(float a, float b) {
    union { __hip_bfloat162 h2; unsigned u; } c;
    c.h2 = __float22bfloat162_rn(make_float2(a, b));
    return c.u;
}
// async global->LDS DMA, 16 B per lane; LDS dest = wave-uniform base + lane*16
static __device__ __forceinline__ void gl_lds16(const void* g, void* l) {
    __builtin_amdgcn_global_load_lds(
        (const __attribute__((address_space(1))) void*)g,
        (__attribute__((address_space(3))) void*)l, 16, 0, 0);
}
// convert 16 consecutive fp32 (two float4 pairs) to one bf16x8 fragment
static __device__ __forceinline__ bf16x8 cvt8(const float* p) {
    float4 a = ((const float4*)p)[0];
    float4 b = ((const float4*)p)[1];
    union { unsigned u[4]; bf16x8 v; } c;
    c.u[0] = pk2bf(a.x, a.y); c.u[1] = pk2bf(a.z, a.w);
    c.u[2] = pk2bf(b.x, b.y); c.u[3] = pk2bf(b.z, b.w);
    return c.v;
}

// ---------------------------------------------------------------------------
// Kernel 1 (R5 mega-proj): grid = (1024, 4), block = 256.
//   which 0/1: Q/K projection, C = X·W^T  (R4 hybrid: X-frags direct from
//              global, W staged once in LDS). Out layout [B,H,S,DH].
//   which 2  : V projection TRANSPOSED, C = W·X^T (operand swap) — emits
//              C[d][s] directly into vt[bh][d][s]: the old vtrans stage is
//              deleted. Block = (bh, 64-s tile); A-frags = Wv rows from LDS,
//              B-frags = X rows direct from global (col-lane = s).
//   which 3  : blk<512 maskpack (int4 form) | blk>=512 Wo fp32->bf16.
// ---------------------------------------------------------------------------
__global__ __launch_bounds__(256) void proj_mfma(
    const float* __restrict__ q, const float* __restrict__ k, const float* __restrict__ v,
    const float* __restrict__ Wq, const float* __restrict__ bq,
    const float* __restrict__ Wk, const float* __restrict__ bk,
    const float* __restrict__ Wv, const float* __restrict__ bv,
    unsigned short* __restrict__ qh, unsigned short* __restrict__ kh,
    unsigned short* __restrict__ vt,
    const int* __restrict__ mask, u64* __restrict__ bits,
    const float* __restrict__ Wo, unsigned short* __restrict__ Wob)
{
    const int blk   = blockIdx.x;
    const int which = blockIdx.y;
    const int t     = threadIdx.x;

    if (which == 3) {                     // ---- prep jobs (no LDS, no barrier) ----
        if (blk < 512) {                  // mask -> bitmask
            const int idx = blk * 256 + t;
            const int4* src = (const int4*)(mask + (size_t)idx * 64);
            u64 wb = 0;
#pragma unroll
            for (int u = 0; u < 16; ++u) {
                int4 m = src[u];
                u64 nib = (m.x != 0 ? 1ull : 0) | (m.y != 0 ? 2ull : 0) |
                          (m.z != 0 ? 4ull : 0) | (m.w != 0 ? 8ull : 0);
                wb |= nib << (u * 4);
            }
            bits[idx] = wb;
        } else {                          // Wo fp32 -> bf16
            const int i = ((blk - 512) * 256 + t) * 8;
            float4 a = ((const float4*)(Wo + i))[0];
            float4 b = ((const float4*)(Wo + i))[1];
            unsigned o32[4] = {pk2bf(a.x, a.y), pk2bf(a.z, a.w),
                               pk2bf(b.x, b.y), pk2bf(b.z, b.w)};
            *(uint4*)(Wob + i) = *(uint4*)o32;
        }
        return;
    }

    const float* x; const float* W; const float* bias;
    if (which == 0)      { x = q; W = Wq; bias = bq; }
    else if (which == 1) { x = k; W = Wk; bias = bk; }
    else                 { x = v; W = Wv; bias = bv; }

    __shared__ unsigned short Ws[64 * 72];

    const int w    = t >> 6;
    const int lane = t & 63;
    const int l15  = lane & 15;
    const int quad = lane >> 4;

    // ---- stage W into LDS (cooperative, one pass; verified R2 layout) ----
    const int sr = t >> 2, sp = t & 3;
    {
        const float* wsrc = W + (size_t)sr * 64 + sp * 16;
        unsigned o32[8];
#pragma unroll
        for (int u4 = 0; u4 < 4; ++u4) {
            float4 a = ((const float4*)wsrc)[u4];
            o32[u4 * 2 + 0] = pk2bf(a.x, a.y);
            o32[u4 * 2 + 1] = pk2bf(a.z, a.w);
        }
        *(uint4*)&Ws[sr * 72 + sp * 16]     = *(uint4*)&o32[0];
        *(uint4*)&Ws[sr * 72 + sp * 16 + 8] = *(uint4*)&o32[4];
    }

    if (which == 2) {                     // ---- V: C = W·X^T -> vt[bh][d][s] ----
        const int bh = blk >> 5;          // (b,h) 0..31
        const int st = blk & 31;          // s-tile
        const int b  = bh >> 4, h = bh & 15;
        const int s  = st * 64 + w * 16 + l15;

        // B-frags: col n = l15 = s-within-16, k = quad*8.. (X row s, head h)
        const float* xrow = x + ((size_t)(b * SEQ + s)) * EMBED + h * DH;
        const bf16x8 bx0 = cvt8(xrow + quad * 8);
        const bf16x8 bx1 = cvt8(xrow + 32 + quad * 8);

        __syncthreads();

#pragma unroll
        for (int nt = 0; nt < 4; ++nt) {
            // A-frags: row m = l15 = d-within-16 (Wv row d), k = quad*8..
            bf16x8 aw0 = *(const bf16x8*)&Ws[(nt * 16 + l15) * 72 + quad * 8];
            bf16x8 aw1 = *(const bf16x8*)&Ws[(nt * 16 + l15) * 72 + 32 + quad * 8];
            f32x4 a = {0, 0, 0, 0};
            a = __builtin_amdgcn_mfma_f32_16x16x32_bf16(aw0, bx0, a, 0, 0, 0);
            a = __builtin_amdgcn_mfma_f32_16x16x32_bf16(aw1, bx1, a, 0, 0, 0);
            // C row = quad*4+r = d-within-16, col = l15 = s-within-16
#pragma unroll
            for (int r = 0; r < 4; ++r) {
                const int d = nt * 16 + quad * 4 + r;
                vt[((size_t)bh * DH + d) * SEQ + s] = f2bf(a[r] + bias[d]);
            }
        }
        return;
    }

    // ---- Q/K: C = X·W^T (R4 hybrid path) ----
    const float oscale = (which == 0) ? QSCALE : 1.0f;
    unsigned short* out = (which == 0) ? qh : kh;

    const float* xrow = x + ((size_t)blk * 64 + w * 16 + l15) * 64;
    const bf16x8 af0 = cvt8(xrow + quad * 8);
    const bf16x8 af1 = cvt8(xrow + 32 + quad * 8);

    __syncthreads();

    f32x4 acc[4];
#pragma unroll
    for (int nt = 0; nt < 4; ++nt) {
        bf16x8 bf0 = *(const bf16x8*)&Ws[(nt * 16 + l15) * 72 + quad * 8];
        bf16x8 bf1 = *(const bf16x8*)&Ws[(nt * 16 + l15) * 72 + 32 + quad * 8];
        f32x4 a = {0, 0, 0, 0};
        a = __builtin_amdgcn_mfma_f32_16x16x32_bf16(af0, bf0, a, 0, 0, 0);
        a = __builtin_amdgcn_mfma_f32_16x16x32_bf16(af1, bf1, a, 0, 0, 0);
        acc[nt] = a;
    }

    const int bsidx = blk * 4 + w;
    const int b = bsidx >> 11, s = bsidx & 2047;
#pragma unroll
    for (int nt = 0; nt < 4; ++nt) {
        const int d = nt * 16 + l15;
        const float bb = bias[d];
#pragma unroll
        for (int r = 0; r < 4; ++r) {
            const int h = quad * 4 + r;
            out[(((size_t)b * HEADS + h) * SEQ + s) * DH + d] =
                f2bf((acc[nt][r] + bb) * oscale);
        }
    }
}

// ---------------------------------------------------------------------------
// Kernel 2: MFMA flash attention, double-buffered DMA K-loop, NO split-K.
// (frozen since R2 — control; 85 us, MfmaUtil 30, conflicts 8.39M)
// ---------------------------------------------------------------------------
__global__ __launch_bounds__(256, 4) void attn_kernel(
    const unsigned short* __restrict__ qh, const unsigned short* __restrict__ kh,
    const unsigned short* __restrict__ vt, const u64* __restrict__ mbits,
    unsigned short* __restrict__ ctx)
{
    const int bid = blockIdx.x;
    const int bh  = bid & 31;
    const int q0  = (bid >> 5) * 64;
    const int b   = bh >> 4;

    __shared__ unsigned char smem[32768];   // buf(16K) x2: [K 8K | V 8K]

    const int t    = threadIdx.x;
    const int w    = t >> 6;              // wave id: q-subtile (16 rows)
    const int lane = t & 63;
    const int l15  = lane & 15;
    const int quad = lane >> 4;

    const int srow   = lane >> 3;
    const int schunk = (lane & 7) ^ srow;

    const unsigned short* qb = qh + ((size_t)bh * SEQ + q0 + w * 16 + l15) * DH + quad * 8;
    const bf16x8 qf0 = *(const bf16x8*)qb;
    const bf16x8 qf1 = *(const bf16x8*)(qb + 32);

    f32x4 O[4];
#pragma unroll
    for (int dt = 0; dt < 4; ++dt) O[dt] = f32x4{0, 0, 0, 0};
    f32x4 Osum = {0, 0, 0, 0};
    const bf16x4 ones = {(short)0x3F80, (short)0x3F80, (short)0x3F80, (short)0x3F80};

    const unsigned short* kbase = kh + (size_t)bh * SEQ * DH
                                  + (size_t)srow * DH + schunk * 8;
    const unsigned short* vbase = vt + (size_t)bh * DH * SEQ
                                  + (size_t)srow * SEQ + schunk * 8;
    const u64* mrow = mbits + ((size_t)b * SEQ + q0 + w * 16 + l15) * (SEQ / 64);

    if (w < 2) {
        unsigned char* Kd = smem;
#pragma unroll
        for (int j = 0; j < 4; ++j) {
            const int i = w * 4 + j;
            gl_lds16(kbase + (size_t)i * 8 * DH, Kd + i * 1024);
        }
    } else {
        unsigned char* Vd = smem + 8192;
#pragma unroll
        for (int j = 0; j < 4; ++j) {
            const int i = (w - 2) * 4 + j;
            gl_lds16(vbase + (size_t)i * 8 * SEQ, Vd + i * 1024);
        }
    }
    u64 pm = mrow[0];
    __syncthreads();                      // drains DMA(0)

    for (int kt = 0; kt < 32; ++kt) {
        if (kt < 31) {
            const int bn = (kt + 1) & 1;
            if (w < 2) {
                unsigned char* Kd = smem + bn * 16384;
                const unsigned short* g0 = kbase + (size_t)(kt + 1) * 64 * DH;
#pragma unroll
                for (int j = 0; j < 4; ++j) {
                    const int i = w * 4 + j;
                    gl_lds16(g0 + (size_t)i * 8 * DH, Kd + i * 1024);
                }
            } else {
                unsigned char* Vd = smem + bn * 16384 + 8192;
                const unsigned short* g0 = vbase + (kt + 1) * 64;
#pragma unroll
                for (int j = 0; j < 4; ++j) {
                    const int i = (w - 2) * 4 + j;
                    gl_lds16(g0 + (size_t)i * 8 * SEQ, Vd + i * 1024);
                }
            }
        }
        const u64 mb = pm;
        if (kt < 31) pm = mrow[kt + 1];

        const unsigned short* KtH = (const unsigned short*)(smem + (kt & 1) * 16384);
        const unsigned short* VtH = KtH + 4096;

        const u64 mq = mb >> (quad * 4);
        bf16x4 p[4];
        const int rx = l15 & 7;
#pragma unroll
        for (int st = 0; st < 4; ++st) {
            const int r = st * 16 + l15;
            bf16x8 kf0 = *(const bf16x8*)&KtH[r * 64 + ((quad ^ rx)) * 8];
            bf16x8 kf1 = *(const bf16x8*)&KtH[r * 64 + ((quad ^ rx) ^ 4) * 8];
            f32x4 sa = {0, 0, 0, 0};
            sa = __builtin_amdgcn_mfma_f32_16x16x32_bf16(kf0, qf0, sa, 0, 0, 0);
            sa = __builtin_amdgcn_mfma_f32_16x16x32_bf16(kf1, qf1, sa, 0, 0, 0);
            const unsigned nib = (unsigned)(mq >> (st * 16)) & 0xFu;
            float p0 = (nib & 1u) ? exp2f(sa[0]) : 0.f;
            float p1 = (nib & 2u) ? exp2f(sa[1]) : 0.f;
            float p2 = (nib & 4u) ? exp2f(sa[2]) : 0.f;
            float p3 = (nib & 8u) ? exp2f(sa[3]) : 0.f;
            union { unsigned u2[2]; bf16x4 v; } pu;
            pu.u2[0] = pk2bf(p0, p1);
            pu.u2[1] = pk2bf(p2, p3);
            p[st] = pu.v;
            Osum = __builtin_amdgcn_mfma_f32_16x16x16bf16_1k(p[st], ones, Osum, 0, 0, 0);
        }

#pragma unroll
        for (int dt = 0; dt < 4; ++dt) {
            const int d = dt * 16 + l15;
            const int dx = l15 & 7;
#pragma unroll
            for (int st = 0; st < 4; ++st) {
                const int ch = (st * 2 + (quad >> 1)) ^ dx;
                bf16x4 vb = *(const bf16x4*)&VtH[d * 64 + ch * 8 + (quad & 1) * 4];
                O[dt] = __builtin_amdgcn_mfma_f32_16x16x16bf16_1k(p[st], vb, O[dt], 0, 0, 0);
            }
        }
        __syncthreads();
    }

    float inv[4];
#pragma unroll
    for (int r = 0; r < 4; ++r) inv[r] = 1.0f / Osum[r];
#pragma unroll
    for (int r = 0; r < 4; ++r) {
        const int row = q0 + w * 16 + quad * 4 + r;
        unsigned short* dst = ctx + ((size_t)bh * SEQ + row) * DH + l15;
#pragma unroll
        for (int dt = 0; dt < 4; ++dt)
            dst[dt * 16] = f2bf(O[dt][r] * inv[r]);
    }
}

// ---------------------------------------------------------------------------
// Kernel 3: output projection via MFMA, DMA-staged + double-buffered.
// (frozen)
// ---------------------------------------------------------------------------
__global__ __launch_bounds__(256, 4) void outproj_mfma(
    const unsigned short* __restrict__ ctx, const unsigned short* __restrict__ Wob,
    const float* __restrict__ bo, float* __restrict__ out)
{
    const int n0 = blockIdx.x * 64;
    const int m0 = blockIdx.y * 64;
    const int b  = m0 / SEQ;
    const int s0 = m0 % SEQ;

    __shared__ unsigned char smem[32768];   // buf(16K) x2: [A 8K | W 8K]

    const int t    = threadIdx.x;
    const int w    = t >> 6;
    const int lane = t & 63;
    const int l15  = lane & 15;
    const int quad = lane >> 4;
    const int srow   = lane >> 3;
    const int schunk = (lane & 7) ^ srow;

    const unsigned short* abase = ctx + ((size_t)b * HEADS * SEQ + s0 + srow) * DH + schunk * 8;
    const unsigned short* wbase = Wob + (size_t)(n0 + srow) * EMBED + schunk * 8;

    f32x4 acc[4] = {f32x4{0,0,0,0}, f32x4{0,0,0,0}, f32x4{0,0,0,0}, f32x4{0,0,0,0}};

    {
        unsigned char* Ab = smem;
        unsigned char* Wb = smem + 8192;
#pragma unroll
        for (int j = 0; j < 4; ++j) {
            const int idx = w * 4 + j;
            if (idx < 8)
                gl_lds16(abase + (size_t)idx * 8 * DH, Ab + idx * 1024);
            else
                gl_lds16(wbase + (size_t)(idx - 8) * 8 * EMBED, Wb + (idx - 8) * 1024);
        }
    }
    __syncthreads();

    for (int kt = 0; kt < 16; ++kt) {
        if (kt < 15) {
            const int ktn = kt + 1;
            unsigned char* Ab = smem + (ktn & 1) * 16384;
            unsigned char* Wb = Ab + 8192;
#pragma unroll
            for (int j = 0; j < 4; ++j) {
                const int idx = w * 4 + j;
                if (idx < 8)
                    gl_lds16(abase + (size_t)ktn * SEQ * DH + (size_t)idx * 8 * DH,
                             Ab + idx * 1024);
                else
                    gl_lds16(wbase + (size_t)(idx - 8) * 8 * EMBED + ktn * 64,
                             Wb + (idx - 8) * 1024);
            }
        }

        const unsigned short* At = (const unsigned short*)(smem + (kt & 1) * 16384);
        const unsigned short* Wt = At + 4096;
        const int rx = l15 & 7;
        const int c0 = ((quad ^ rx)) * 8;

        bf16x8 bf0 = *(const bf16x8*)&Wt[(w * 16 + l15) * 64 + c0];
        bf16x8 bf1 = *(const bf16x8*)&Wt[(w * 16 + l15) * 64 + (c0 ^ 32)];
#pragma unroll
        for (int mt = 0; mt < 4; ++mt) {
            bf16x8 af0 = *(const bf16x8*)&At[(mt * 16 + l15) * 64 + c0];
            bf16x8 af1 = *(const bf16x8*)&At[(mt * 16 + l15) * 64 + (c0 ^ 32)];
            acc[mt] = __builtin_amdgcn_mfma_f32_16x16x32_bf16(af0, bf0, acc[mt], 0, 0, 0);
            acc[mt] = __builtin_amdgcn_mfma_f32_16x16x32_bf16(af1, bf1, acc[mt], 0, 0, 0);
        }
        __syncthreads();
    }

    const float bv = bo[n0 + w * 16 + l15];
#pragma unroll
    for (int mt = 0; mt < 4; ++mt) {
#pragma unroll
        for (int r = 0; r < 4; ++r) {
            out[(size_t)(m0 + mt * 16 + quad * 4 + r) * EMBED + n0 + w * 16 + l15] =
                acc[mt][r] + bv;
        }
    }
}

// ---------------------------------------------------------------------------
extern "C" void kernel_launch(void* const* d_in, const int* in_sizes, int n_in,
                              void* d_out, int out_size, void* d_ws, size_t ws_size,
                              hipStream_t stream) {
    const float* k    = (const float*)d_in[0];
    const float* q    = (const float*)d_in[1];
    const float* v    = (const float*)d_in[2];
    const int*   mask = (const int*)  d_in[3];
    const float* Wk   = (const float*)d_in[4];
    const float* bk   = (const float*)d_in[5];
    const float* Wq   = (const float*)d_in[6];
    const float* bq   = (const float*)d_in[7];
    const float* Wv   = (const float*)d_in[8];
    const float* bv   = (const float*)d_in[9];
    const float* Wo   = (const float*)d_in[10];
    const float* bo   = (const float*)d_in[11];
    float* out = (float*)d_out;

    const size_t TEN = (size_t)BATCH * HEADS * SEQ * DH;   // 4,194,304 elems
    unsigned short* qh_bf = (unsigned short*)d_ws;         // 8 MB
    unsigned short* kh_bf = qh_bf + TEN;                   // 8 MB
    unsigned short* vt_bf = kh_bf + TEN;                   // 8 MB
    unsigned short* ctxb  = vt_bf + TEN;                   // 8 MB
    unsigned short* Wob   = ctxb + TEN;                    // 2 MB
    u64*            mbits = (u64*)(Wob + EMBED * EMBED);   // 1 MB  (35 MB total)

    proj_mfma<<<dim3(1024, 4), 256, 0, stream>>>(
        q, k, v, Wq, bq, Wk, bk, Wv, bv,
        qh_bf, kh_bf, vt_bf, mask, mbits, Wo, Wob);
    attn_kernel<<<dim3((SEQ / 64) * BATCH * HEADS), 256, 0, stream>>>(
        qh_bf, kh_bf, vt_bf, mbits, ctxb);
    outproj_mfma<<<dim3(EMBED / 64, BATCH * SEQ / 64), 256, 0, stream>>>(
        ctxb, Wob, bo, out);
}